// Round 14
// baseline (37.712 us; speedup 1.0000x reference)
//
#include <hip/hip_runtime.h>
#include <hip/hip_bf16.h>

// QuantumAttention: out[b,s,e] = sum_q q[b,s,q] * W_dec[e,q] + x[b,s,e]
//   angles = x @ W_enc^T, c = cos(angles)
//   q[0] = prod(c[1..7]); q[i] = prod(c[0..i])
//
// R14: MFMA for BOTH matmuls; zero cross-wave deps; one HBM pass.
//  - encode: R13-verbatim (validated) mfma_f32_16x16x32_bf16 over K=1024.
//  - decode: out-tile[16 tok x 16 e] = A_q(16x32, qv bf16 padded) *
//    B_dec(32x16, W_dec bf16 from LDS; k>=8 lanes read zero slot) + C
//    where C = x-tile loaded straight into the accumulator (residual is
//    FREE, and stays f32). 64 independent MFMA tiles per 16 tokens.
//  - each wave owns its 16 tokens end-to-end; qv redistributed through
//    wave-private LDS (DS ops are wave-ordered; no barrier). Only barrier
//    in the kernel is the weight-staging prologue.
//  - decode x-read (C) follows encode A-read of the same rows -> L2-hot.

typedef float v2f __attribute__((ext_vector_type(2)));
typedef float v4f __attribute__((ext_vector_type(4)));
typedef short bf16x8 __attribute__((ext_vector_type(8)));

#define EDIM 1024
#define QDIM 8
#define NTOK 16384
#define BLOCK 256
#define TOKPB 64
#define GRID (NTOK / TOKPB)   // 256 blocks
#define NKK (EDIM / 32)       // 32 K-steps (encode)
#define NET (EDIM / 16)       // 64 e-tiles (decode)

__device__ __forceinline__ short f2bf(float f) {
    __hip_bfloat16 h = __float2bfloat16(f);
    return *reinterpret_cast<short*>(&h);
}

// inclusive product-scan step across lanes 0..7 of each 16-lane row
template<int K>
__device__ __forceinline__ float scan_mul_step(float p, int laneq) {
    int m = __builtin_amdgcn_update_dpp(0, __float_as_int(p), 0x110 | K, 0xF, 0xF, true);
    float tmul = (laneq >= K) ? __int_as_float(m) : 1.0f;
    return p * tmul;
}

__global__ __launch_bounds__(BLOCK, 2)
void qattn_kernel(const float* __restrict__ x,
                  const float* __restrict__ W_enc,   // [Q][E]
                  const float* __restrict__ W_dec,   // [E][Q]
                  float* __restrict__ out)
{
    __shared__ short Benc[NKK * 64 * 8];   // 32 KB encode B-frags (R13 layout)
    __shared__ short Bdec[EDIM * QDIM];    // 16 KB: [e][q] bf16
    __shared__ short Bzero[8];             // 16 B zero slot for k>=8 lanes
    __shared__ float qv_w[4][16][QDIM];    // per-wave qv, 2 KB

    const int t    = threadIdx.x;
    const int lane = t & 63;
    const int wave = t >> 6;
    const int tok0 = blockIdx.x * TOKPB;

    // ---- prologue: stage encode B-frags (R13 verbatim) ----
#pragma unroll
    for (int s8 = 0; s8 < 8; ++s8) {
        const int s  = t * 8 + s8;
        const int kk = s >> 6;
        const int l  = s & 63;
        const int q  = l & 15;
        const int kg = l >> 4;
        bf16x8 bv = (bf16x8){0, 0, 0, 0, 0, 0, 0, 0};
        if (q < QDIM) {
            const float* wp = W_enc + q * EDIM + kk * 32 + kg * 8;
            v4f w0 = *(const v4f*)wp;
            v4f w1 = *(const v4f*)(wp + 4);
            bv[0] = f2bf(w0.x); bv[1] = f2bf(w0.y);
            bv[2] = f2bf(w0.z); bv[3] = f2bf(w0.w);
            bv[4] = f2bf(w1.x); bv[5] = f2bf(w1.y);
            bv[6] = f2bf(w1.z); bv[7] = f2bf(w1.w);
        }
        *(bf16x8*)&Benc[s * 8] = bv;
    }
    // stage decode B: thread t covers e = t*4 .. t*4+3
#pragma unroll
    for (int j = 0; j < 4; ++j) {
        const int e = t * 4 + j;
        v4f a = *(const v4f*)(W_dec + e * QDIM);
        v4f b = *(const v4f*)(W_dec + e * QDIM + 4);
        bf16x8 bv;
        bv[0] = f2bf(a.x); bv[1] = f2bf(a.y);
        bv[2] = f2bf(a.z); bv[3] = f2bf(a.w);
        bv[4] = f2bf(b.x); bv[5] = f2bf(b.y);
        bv[6] = f2bf(b.z); bv[7] = f2bf(b.w);
        *(bf16x8*)&Bdec[e * 8] = bv;
    }
    if (t == 0) *(bf16x8*)&Bzero[0] = (bf16x8){0, 0, 0, 0, 0, 0, 0, 0};
    __syncthreads();   // the only block barrier

    // ---- encode: wave-private 16-token MFMA tile over K=1024 ----
    const int wtok0 = tok0 + wave * 16;
    const int arow  = lane & 15;          // A row / C col index
    const int kg    = lane >> 4;

    v4f acc = (v4f){0.f, 0.f, 0.f, 0.f};
    const float* abase = x + (size_t)(wtok0 + arow) * EDIM + kg * 8;
#pragma unroll 8
    for (int kk = 0; kk < NKK; ++kk) {
        const float* ap = abase + kk * 32;
        v4f a0 = *(const v4f*)ap;
        v4f a1 = *(const v4f*)(ap + 4);
        bf16x8 av;
        av[0] = f2bf(a0.x); av[1] = f2bf(a0.y);
        av[2] = f2bf(a0.z); av[3] = f2bf(a0.w);
        av[4] = f2bf(a1.x); av[5] = f2bf(a1.y);
        av[6] = f2bf(a1.z); av[7] = f2bf(a1.w);
        bf16x8 bv = *(const bf16x8*)&Benc[(kk * 64 + lane) * 8];
        acc = __builtin_amdgcn_mfma_f32_16x16x32_bf16(av, bv, acc, 0, 0, 0);
    }

    // ---- cos + cumprod scan; qv -> wave-private LDS (no barrier) ----
    const int q = lane & 15;
#pragma unroll
    for (int r = 0; r < 4; ++r) {
        const int row = kg * 4 + r;        // token row within tile
        float c = __cosf(acc[r]);

        float p = c;                       // q -> c0*...*cq
        p = scan_mul_step<1>(p, q);
        p = scan_mul_step<2>(p, q);
        p = scan_mul_step<4>(p, q);

        float b = (q == 0) ? 1.0f : c;     // lane 7 -> c1*...*c7
        b = scan_mul_step<1>(b, q);
        b = scan_mul_step<2>(b, q);
        b = scan_mul_step<4>(b, q);

        if (q >= 1 && q < QDIM) qv_w[wave][row][q] = p;
        if (q == 7)             qv_w[wave][row][0] = b;
    }

    // ---- build A_q fragment: row = arow, k = kg*8+j; k>=8 -> zero ----
    bf16x8 aq = (bf16x8){0, 0, 0, 0, 0, 0, 0, 0};
    if (kg == 0) {
        v4f lo = *(const v4f*)&qv_w[wave][arow][0];   // wave-ordered after writes
        v4f hi = *(const v4f*)&qv_w[wave][arow][4];
        aq[0] = f2bf(lo.x); aq[1] = f2bf(lo.y);
        aq[2] = f2bf(lo.z); aq[3] = f2bf(lo.w);
        aq[4] = f2bf(hi.x); aq[5] = f2bf(hi.y);
        aq[6] = f2bf(hi.z); aq[7] = f2bf(hi.w);
    }

    // ---- decode: 64 independent MFMA e-tiles; C = x (residual free) ----
    const size_t rbase = (size_t)(wtok0 + kg * 4) * EDIM;   // lane's 4 C rows
#pragma unroll 8
    for (int j = 0; j < NET; ++j) {
        const int e = j * 16 + arow;
        bf16x8 bq = (kg == 0) ? *(const bf16x8*)&Bdec[e * 8]
                              : *(const bf16x8*)&Bzero[0];
        const float* xc = x + rbase + e;
        v4f cf;
        cf[0] = xc[0];
        cf[1] = xc[EDIM];
        cf[2] = xc[2 * EDIM];
        cf[3] = xc[3 * EDIM];
        v4f d = __builtin_amdgcn_mfma_f32_16x16x32_bf16(aq, bq, cf, 0, 0, 0);
        float* oc = out + rbase + e;
        oc[0]        = d[0];
        oc[EDIM]     = d[1];
        oc[2 * EDIM] = d[2];
        oc[3 * EDIM] = d[3];
    }
}

extern "C" void kernel_launch(void* const* d_in, const int* in_sizes, int n_in,
                              void* d_out, int out_size, void* d_ws, size_t ws_size,
                              hipStream_t stream) {
    const float* x     = (const float*)d_in[0];
    const float* W_enc = (const float*)d_in[1];
    const float* W_dec = (const float*)d_in[2];
    float* out         = (float*)d_out;
    (void)d_ws; (void)ws_size;

    hipLaunchKernelGGL(qattn_kernel, dim3(GRID), dim3(BLOCK), 0, stream,
                       x, W_enc, W_dec, out);
}